// Round 11
// baseline (155.669 us; speedup 1.0000x reference)
//
#include <hip/hip_runtime.h>

#define EPS_W 1e-6f

__device__ __forceinline__ float fast_rsq(float x) { return __builtin_amdgcn_rsqf(x); }
__device__ __forceinline__ float fast_rcp(float x) { return __builtin_amdgcn_rcpf(x); }

// ---------------------------------------------------------------------------
// Horn-quaternion solve via 5-sweep cyclic Jacobi on N (4x4).
// IDENTICAL to rounds 7-10 verified version (absmax 0.0039).
// ---------------------------------------------------------------------------
__device__ __forceinline__ void solve16(const float S[16], float R[9], float t[3])
{
    const float sw  = S[0];
    const float Sa0 = S[1], Sa1 = S[2], Sa2 = S[3];
    const float Sb0 = S[4], Sb1 = S[5], Sb2 = S[6];

    const float inv = fast_rcp(sw + EPS_W);
    const float cA0 = Sa0*inv, cA1 = Sa1*inv, cA2 = Sa2*inv;
    const float cB0 = Sb0*inv, cB1 = Sb1*inv, cB2 = Sb2*inv;

    float H[3][3];
    H[0][0] = S[7]  - cA0*Sb0 - Sa0*cB0 + sw*cA0*cB0;
    H[0][1] = S[8]  - cA0*Sb1 - Sa0*cB1 + sw*cA0*cB1;
    H[0][2] = S[9]  - cA0*Sb2 - Sa0*cB2 + sw*cA0*cB2;
    H[1][0] = S[10] - cA1*Sb0 - Sa1*cB0 + sw*cA1*cB0;
    H[1][1] = S[11] - cA1*Sb1 - Sa1*cB1 + sw*cA1*cB1;
    H[1][2] = S[12] - cA1*Sb2 - Sa1*cB2 + sw*cA1*cB2;
    H[2][0] = S[13] - cA2*Sb0 - Sa2*cB0 + sw*cA2*cB0;
    H[2][1] = S[14] - cA2*Sb1 - Sa2*cB1 + sw*cA2*cB1;
    H[2][2] = S[15] - cA2*Sb2 - Sa2*cB2 + sw*cA2*cB2;

    const float Sxx=H[0][0], Sxy=H[0][1], Sxz=H[0][2];
    const float Syx=H[1][0], Syy=H[1][1], Syz=H[1][2];
    const float Szx=H[2][0], Szy=H[2][1], Szz=H[2][2];

    float Nm[4][4];
    Nm[0][0] =  Sxx+Syy+Szz; Nm[0][1] = Syz-Szy;      Nm[0][2] = Szx-Sxz;      Nm[0][3] = Sxy-Syx;
    Nm[1][0] =  Nm[0][1];    Nm[1][1] = Sxx-Syy-Szz;  Nm[1][2] = Sxy+Syx;      Nm[1][3] = Szx+Sxz;
    Nm[2][0] =  Nm[0][2];    Nm[2][1] = Nm[1][2];     Nm[2][2] = -Sxx+Syy-Szz; Nm[2][3] = Syz+Szy;
    Nm[3][0] =  Nm[0][3];    Nm[3][1] = Nm[1][3];     Nm[3][2] = Nm[2][3];     Nm[3][3] = -Sxx-Syy+Szz;

    float Vv[4][4] = {{1.f,0.f,0.f,0.f},{0.f,1.f,0.f,0.f},{0.f,0.f,1.f,0.f},{0.f,0.f,0.f,1.f}};

    for (int sweep = 0; sweep < 5; ++sweep) {
        #pragma unroll
        for (int pair = 0; pair < 6; ++pair) {
            constexpr int PP[6] = {0,0,0,1,1,2};
            constexpr int QQ[6] = {1,2,3,2,3,3};
            const int p = PP[pair], q = QQ[pair];
            float d  = Nm[p][p] - Nm[q][q];
            float o  = Nm[p][q];
            float r2 = d*d + 4.f*o*o;
            bool tiny = r2 < 1e-30f;
            float rinv = fast_rsq(tiny ? 1.f : r2);
            float hh = 0.5f + 0.5f * fabsf(d) * rinv;
            float ci = fast_rsq(hh);
            float c  = hh * ci;
            float s  = (d < 0.f ? o : -o) * rinv * ci;
            c = tiny ? 1.f : c;
            s = tiny ? 0.f : s;
            #pragma unroll
            for (int k = 0; k < 4; ++k) {
                float akp = Nm[k][p], akq = Nm[k][q];
                Nm[k][p] = c*akp - s*akq;
                Nm[k][q] = s*akp + c*akq;
            }
            #pragma unroll
            for (int k = 0; k < 4; ++k) {
                float apk = Nm[p][k], aqk = Nm[q][k];
                Nm[p][k] = c*apk - s*aqk;
                Nm[q][k] = s*apk + c*aqk;
            }
            #pragma unroll
            for (int k = 0; k < 4; ++k) {
                float vkp = Vv[k][p], vkq = Vv[k][q];
                Vv[k][p] = c*vkp - s*vkq;
                Vv[k][q] = s*vkp + c*vkq;
            }
        }
    }

    float q0=Vv[0][0], q1=Vv[1][0], q2=Vv[2][0], q3=Vv[3][0];
    float best = Nm[0][0];
    #pragma unroll
    for (int m = 1; m < 4; ++m) {
        bool bt = Nm[m][m] > best;
        best = bt ? Nm[m][m] : best;
        q0 = bt ? Vv[0][m] : q0;
        q1 = bt ? Vv[1][m] : q1;
        q2 = bt ? Vv[2][m] : q2;
        q3 = bt ? Vv[3][m] : q3;
    }
    float qn = fast_rsq(q0*q0 + q1*q1 + q2*q2 + q3*q3);
    q0*=qn; q1*=qn; q2*=qn; q3*=qn;

    float R00 = q0*q0+q1*q1-q2*q2-q3*q3;
    float R01 = 2.f*(q1*q2 - q0*q3);
    float R02 = 2.f*(q1*q3 + q0*q2);
    float R10 = 2.f*(q1*q2 + q0*q3);
    float R11 = q0*q0-q1*q1+q2*q2-q3*q3;
    float R12 = 2.f*(q2*q3 - q0*q1);
    float R20 = 2.f*(q1*q3 - q0*q2);
    float R21 = 2.f*(q2*q3 + q0*q1);
    float R22 = q0*q0-q1*q1-q2*q2+q3*q3;

    float trRH  = R00*Sxx+R01*Syx+R02*Szx
                + R10*Sxy+R11*Syy+R12*Szy
                + R20*Sxz+R21*Syz+R22*Szz;
    float trRtH = R00*Sxx+R01*Sxy+R02*Sxz
                + R10*Syx+R11*Syy+R12*Syz
                + R20*Szx+R21*Szy+R22*Szz;
    if (trRtH > trRH) {
        float tt;
        tt = R01; R01 = R10; R10 = tt;
        tt = R02; R02 = R20; R20 = tt;
        tt = R12; R12 = R21; R21 = tt;
    }

    R[0]=R00; R[1]=R01; R[2]=R02;
    R[3]=R10; R[4]=R11; R[5]=R12;
    R[6]=R20; R[7]=R21; R[8]=R22;
    t[0] = cB0 - (R00*cA0 + R01*cA1 + R02*cA2);
    t[1] = cB1 - (R10*cA0 + R11*cA1 + R12*cA2);
    t[2] = cB2 - (R20*cA0 + R21*cA1 + R22*cA2);
}

// ---------------------------------------------------------------------------
// v11: r10 structure with ONE change -- global loads are fully coalesced
// float2 slab loads staged through an 8KB reused LDS buffer (W->A->B per
// 32-item group). Intra-wave LDS: no __syncthreads anywhere (lockstep +
// compiler lgkmcnt). Everything else (accumulate, shfl combine, sums stash,
// 64-lane solve, coalesced output) is r10 verbatim.
//  - stage rows padded: A/B stride 31 float2 (62 f), W stride 11 float2:
//    writes ~2-way banks (free), reads ~4-way (1.58x) -- vs 64-line/instr
//    scatter of the strided path (~10x fewer L1/L2 line transactions).
// ---------------------------------------------------------------------------
__global__ __launch_bounds__(64, 4) void kabsch_stg20_kernel(
    const float* __restrict__ A, const float* __restrict__ B,
    const float* __restrict__ W, float* __restrict__ Out, int bs)
{
    __shared__ float2 stg[32 * 31];        // 7936 B, reused W->A->B per group
    __shared__ float  sums[64 * 17];       // 4352 B

    const int lane = threadIdx.x;          // 0..63
    const int base = blockIdx.x * 64;
    const int i = lane >> 1;               // item-in-group, 0..31
    const int h = lane & 1;                // half: points 0..9 / 10..19

    const float2* A2 = reinterpret_cast<const float2*>(A);
    const float2* B2 = reinterpret_cast<const float2*>(B);
    const float2* W2 = reinterpret_cast<const float2*>(W);
    const int bs30 = bs * 30;
    const int bs10 = bs * 10;

    #pragma unroll
    for (int grp = 0; grp < 2; ++grp) {
        const int gbase = base + grp * 32;     // first item of this group

        // ---- stage W (5 coalesced f2 loads), read to regs ----
        #pragma unroll
        for (int s = 0; s < 5; ++s) {
            int g  = s * 64 + lane;            // 0..319
            int gf = gbase * 10 + g;
            gf = gf < bs10 ? gf : bs10 - 1;
            int it = g / 10, c = g - it * 10;
            stg[it * 11 + c] = W2[gf];
        }
        float2 wv2[5];
        #pragma unroll
        for (int j = 0; j < 5; ++j) wv2[j] = stg[i * 11 + h * 5 + j];

        // ---- stage A (15 coalesced f2 loads), read half-item to regs ----
        #pragma unroll
        for (int s = 0; s < 15; ++s) {
            int g  = s * 64 + lane;            // 0..959
            int gf = gbase * 30 + g;
            gf = gf < bs30 ? gf : bs30 - 1;
            int it = g / 30, c = g - it * 30;
            stg[it * 31 + c] = A2[gf];
        }
        float2 av[15];
        #pragma unroll
        for (int j = 0; j < 15; ++j) av[j] = stg[i * 31 + h * 15 + j];

        // ---- stage B, read half-item to regs ----
        #pragma unroll
        for (int s = 0; s < 15; ++s) {
            int g  = s * 64 + lane;
            int gf = gbase * 30 + g;
            gf = gf < bs30 ? gf : bs30 - 1;
            int it = g / 30, c = g - it * 30;
            stg[it * 31 + c] = B2[gf];
        }
        float2 bv[15];
        #pragma unroll
        for (int j = 0; j < 15; ++j) bv[j] = stg[i * 31 + h * 15 + j];

        // ---- accumulate 10 points (r4/7/10-verified math) ----
        float S[16];
        #pragma unroll
        for (int k = 0; k < 16; ++k) S[k] = 0.f;

        #pragma unroll
        for (int g = 0; g < 5; ++g) {
            float2 a0 = av[3*g+0], a1 = av[3*g+1], a2 = av[3*g+2];
            float2 b0 = bv[3*g+0], b1 = bv[3*g+1], b2 = bv[3*g+2];
            float w0 = wv2[g].x < 0.f ? 0.f : wv2[g].x;
            float w1 = wv2[g].y < 0.f ? 0.f : wv2[g].y;
            {   // point 0: (a0.x, a0.y, a1.x)
                float ax=a0.x, ay=a0.y, az=a1.x;
                float bx=b0.x, by=b0.y, bz=b1.x;
                S[0] += w0;
                float wax=w0*ax, way=w0*ay, waz=w0*az;
                S[1]+=wax; S[2]+=way; S[3]+=waz;
                S[4]+=w0*bx; S[5]+=w0*by; S[6]+=w0*bz;
                S[7] +=wax*bx; S[8] +=wax*by; S[9] +=wax*bz;
                S[10]+=way*bx; S[11]+=way*by; S[12]+=way*bz;
                S[13]+=waz*bx; S[14]+=waz*by; S[15]+=waz*bz;
            }
            {   // point 1: (a1.y, a2.x, a2.y)
                float ax=a1.y, ay=a2.x, az=a2.y;
                float bx=b1.y, by=b2.x, bz=b2.y;
                S[0] += w1;
                float wax=w1*ax, way=w1*ay, waz=w1*az;
                S[1]+=wax; S[2]+=way; S[3]+=waz;
                S[4]+=w1*bx; S[5]+=w1*by; S[6]+=w1*bz;
                S[7] +=wax*bx; S[8] +=wax*by; S[9] +=wax*bz;
                S[10]+=way*bx; S[11]+=way*by; S[12]+=way*bz;
                S[13]+=waz*bx; S[14]+=waz*by; S[15]+=waz*bz;
            }
        }

        // ---- pair combine (lanes 2i <-> 2i+1), even lane stashes ----
        #pragma unroll
        for (int k = 0; k < 16; ++k) S[k] += __shfl_xor(S[k], 1);

        if (h == 0) {
            const int row = grp * 32 + i;
            #pragma unroll
            for (int k = 0; k < 16; ++k) sums[row * 17 + k] = S[k];
        }
    }

    // ---- every lane solves one item (lockstep wave => stash complete) ----
    float Ss[16];
    #pragma unroll
    for (int k = 0; k < 16; ++k) Ss[k] = sums[lane * 17 + k];

    float R[9], t[3];
    solve16(Ss, R, t);

    // restage output in LDS (reuse sums; wave lockstep => reads done)
    {
        float* o = &sums[lane * 17];
        o[0]=R[0];  o[1]=R[1];  o[2]=R[2];  o[3]=t[0];
        o[4]=R[3];  o[5]=R[4];  o[6]=R[5];  o[7]=t[1];
        o[8]=R[6];  o[9]=R[7];  o[10]=R[8]; o[11]=t[2];
        o[12]=0.f;  o[13]=0.f;  o[14]=0.f;  o[15]=1.f;
    }

    // coalesced output: 4 float4 per lane
    float4* Og = reinterpret_cast<float4*>(Out) + (size_t)base * 4;
    #pragma unroll
    for (int j2 = 0; j2 < 4; ++j2) {
        const int j  = j2 * 64 + lane;     // float4 index within block
        const int it = j >> 2;
        if (base + it < bs) {
            const float* o = &sums[it * 17 + (j & 3) * 4];
            Og[j] = make_float4(o[0], o[1], o[2], o[3]);
        }
    }
}

// ---------------------------------------------------------------------------
// Generic fallback (any n): 1 thread per item, scalar loads.
// ---------------------------------------------------------------------------
__global__ __launch_bounds__(256) void kabsch_generic_kernel(
    const float* __restrict__ A, const float* __restrict__ B,
    const float* __restrict__ W, float* __restrict__ Out,
    int bs, int n)
{
    const int b = blockIdx.x * blockDim.x + threadIdx.x;
    if (b >= bs) return;

    float S[16];
    #pragma unroll
    for (int k = 0; k < 16; ++k) S[k] = 0.f;

    for (int j = 0; j < n; ++j) {
        const float* ap = A + ((size_t)b * n + j) * 3;
        const float* bp = B + ((size_t)b * n + j) * 3;
        float w = W[(size_t)b * n + j];
        w = w < 0.f ? 0.f : w;
        float ax=ap[0], ay=ap[1], az=ap[2];
        float bx=bp[0], by=bp[1], bz=bp[2];
        S[0] += w;
        float wax = w*ax, way = w*ay, waz = w*az;
        S[1] += wax; S[2] += way; S[3] += waz;
        S[4] += w*bx; S[5] += w*by; S[6] += w*bz;
        S[7] += wax*bx; S[8]  += wax*by; S[9]  += wax*bz;
        S[10]+= way*bx; S[11] += way*by; S[12] += way*bz;
        S[13]+= waz*bx; S[14] += waz*by; S[15] += waz*bz;
    }

    float R[9], t[3];
    solve16(S, R, t);

    float4* O4 = reinterpret_cast<float4*>(Out + (size_t)b * 16);
    O4[0] = make_float4(R[0], R[1], R[2], t[0]);
    O4[1] = make_float4(R[3], R[4], R[5], t[1]);
    O4[2] = make_float4(R[6], R[7], R[8], t[2]);
    O4[3] = make_float4(0.f, 0.f, 0.f, 1.f);
}

extern "C" void kernel_launch(void* const* d_in, const int* in_sizes, int n_in,
                              void* d_out, int out_size, void* d_ws, size_t ws_size,
                              hipStream_t stream) {
    const float* A = (const float*)d_in[0];
    const float* B = (const float*)d_in[1];
    const float* W = (const float*)d_in[2];
    float* Out = (float*)d_out;
    const int bs = out_size / 16;
    const int n  = (bs > 0) ? (in_sizes[2] / bs) : 0;
    if (n == 20) {
        const int blocks = (bs + 63) / 64;
        hipLaunchKernelGGL(kabsch_stg20_kernel, dim3(blocks), dim3(64), 0, stream,
                           A, B, W, Out, bs);
    } else {
        const int blocks = (bs + 255) / 256;
        hipLaunchKernelGGL(kabsch_generic_kernel, dim3(blocks), dim3(256), 0, stream,
                           A, B, W, Out, bs, n);
    }
}